// Round 1
// baseline (165.546 us; speedup 1.0000x reference)
//
#include <hip/hip_runtime.h>
#include <math.h>

#define HH 1024
#define WW 1024
#define OUTW 58            // output columns per wave (64 lanes - 6 halo)
#define RPB 4              // output rows per WAVE (vertical slide length)
#define WPB 4              // waves per block (independent y-strips, no barrier)
#define OFF(i) ((i)*8 - (i)*((i)-1)/2)   // packed upper-tri row offset

// ===== R17: register-prefetch software pipeline =====
// Hard-won constraints (rounds 4..16) still in force:
//  - VGPR bucket MUST stay 128 (phase-B peak: C60+W36+t2a12+pma12+cf8).
//    WRITE_SIZE ~13.5 MB is the no-spill invariant.
//  - Cross-lane ops (DPP/bpermute) never inside divergent flow (r8).
//  - No LDS prefetch: s_waitcnt vmcnt(0) drains output stores (r15).
//    Register prefetch avoids this: compiler emits counted vmcnt(N).
//  - TLP up/down and packed fp32 regressed (r10/r13/r16).
// R17 changes:
//  - Loop rotated: row loads for iter y+1 issue mid-iter-y.
//    prefA (HBM-cold add-row) issues between htap-AtA and the solve
//    (solve = low-density serial chain = free VMEM shadow).
//    prefS (L2-warm sub-row) issues between solve and AtY taps.
//    Prefetch regs live only in phases C/D, NOT at the phase-B peak.
//  - idv[8] folded into W diagonal (identical numerics, -8 regs in C).
//  - 6-row preload + iter-y0 skips subtract (removes the exact add/sub
//    cancellation of row y0-4): -2 row-accumulations per wave.

// DPP move, bound_ctrl=1 (invalid lanes read 0)
template<int CTRL>
__device__ __forceinline__ float dpp0(float x) {
    return __int_as_float(
        __builtin_amdgcn_update_dpp(0, __float_as_int(x), CTRL, 0xf, 0xf, true));
}
// whole-wave shift right by 1 lane (crosses 16-lane row boundaries)
__device__ __forceinline__ float wshr1(float x) { return dpp0<0x138>(x); }

// fp32 reciprocal: v_rcp_f32 + 1 Newton step (~1ulp); LDL^T is sqrt-free
__device__ __forceinline__ float frcp_fast(float s) {
    float r = __builtin_amdgcn_rcpf(s);
    return r * fmaf(-s, r, 2.0f);
}

__global__ __launch_bounds__(WPB * 64, 2) void ls_sep_kernel(
    const float* __restrict__ inp,    // [3,H,W]
    const float* __restrict__ dep,    // [1,H,W]
    const float* __restrict__ alb,    // [3,H,W]
    const float* __restrict__ nrm,    // [3,H,W]
    float* __restrict__ out)          // [3,H,W]
{
    const int L  = threadIdx.x & 63;          // lane 0..63
    const int wv = threadIdx.x >> 6;          // wave 0..3 (independent y-strip)
    const int HW = HH * WW;
    // lane L sums column x; its horizontal window (x-6..x) is centered at x-3
    const int x  = OUTW * blockIdx.x - 3 + L;
    const int y0 = (RPB * WPB) * blockIdx.y + RPB * wv;
    const int px = x - 3;                     // output pixel column for this lane

    const int xc    = min(max(x, 0), WW - 1);
    const float xok = (x >= 0 && x < WW) ? 1.f : 0.f;

    float C[60];                              // running column sums (7 rows in y)
    #pragma unroll
    for (int k = 0; k < 60; k++) C[k] = 0.f;

    // clamped-address loads only; no C update (prefetchable)
    auto load_row = [&](int yy, float (&fv)[8], float (&yv)[3]) {
        const int yc = min(max(yy, 0), HH - 1);
        const int p = yc * WW + xc;
        fv[0] = 1.f;
        fv[1] = dep[p];
        fv[2] = alb[p];
        fv[3] = alb[p + HW];
        fv[4] = alb[p + 2 * HW];
        fv[5] = nrm[p];
        fv[6] = nrm[p + HW];
        fv[7] = nrm[p + 2 * HW];
        yv[0] = inp[p];
        yv[1] = inp[p + HW];
        yv[2] = inp[p + 2 * HW];
    };

    // masked accumulate of a loaded row into the column sums
    auto apply_row = [&](const float (&fv)[8], const float (&yv)[3],
                         int yy, float sgn) {
        const float ok = (yy >= 0 && yy < HH) ? xok : 0.f;
        const float s = sgn * ok;
        float fs[8];
        #pragma unroll
        for (int i = 0; i < 8; i++) fs[i] = fv[i] * s;
        int k = 0;
        #pragma unroll
        for (int i = 0; i < 8; i++)
            #pragma unroll
            for (int j = i; j < 8; j++) { C[k] = fmaf(fs[i], fv[j], C[k]); k++; }
        #pragma unroll
        for (int i = 0; i < 8; i++)
            #pragma unroll
            for (int c = 0; c < 3; c++)
                C[36 + i * 3 + c] = fmaf(fs[i], yv[c], C[36 + i * 3 + c]);
    };

    // prologue prefetch of iter-y0's add-row: fully covered by the preload
    float pAf[8], pAy[3];
    load_row(y0 + 3, pAf, pAy);

    // preload rows y0-3 .. y0+2 (iter y0 skips the subtract; window y0-3..y0+3)
    #pragma unroll 1
    for (int yy = y0 - 3; yy < y0 + 3; yy++) {
        float fv[8], yv[3];
        load_row(yy, fv, yv);
        apply_row(fv, yv, yy, 1.f);
    }

    float pSf[8], pSy[3];                     // first written in iter y0,
                                              // first read in iter y0+1

    const int idxm4 = ((L - 4) & 63) << 2;    // bpermute byte index for lane L-4
    const int pxc = min(max(px, 0), WW - 1);
    const bool do_store = (L >= 6) && (px < WW);

    // Batched horizontal 7-tap over lanes L-6..L for 12 values at once.
    // MUST be called by all 64 lanes (cross-lane inside).
    auto htap12 = [&](int base, float* dst) {
        float t2a[12];
        int pma[12];
        #pragma unroll
        for (int j = 0; j < 12; j++) {
            const float xv = C[base + j];
            const float w1 = wshr1(xv);       // C(L-1)
            const float t1 = xv + w1;         // L-1..L
            const float w2 = wshr1(w1);       // C(L-2)
            const float t3 = t1 + w2;         // L-2..L
            const float w3 = wshr1(w2);       // C(L-3)
            t2a[j] = t3 + w3;                 // L-3..L
            pma[j] = __builtin_amdgcn_ds_bpermute(idxm4, __float_as_int(t3));
        }
        #pragma unroll
        for (int j = 0; j < 12; j++)
            dst[j] = t2a[j] + __int_as_float(pma[j]);   // + (L-6..L-4)
    };

    #pragma unroll 1
    for (int y = y0; y < y0 + RPB; y++) {
        // ---- consume prefetched rows ----
        apply_row(pAf, pAy, y + 3, 1.f);
        if (y > y0) apply_row(pSf, pSy, y - 4, -1.f);   // wave-uniform branch

        // center-pixel features EARLY: L1/L2-hit latency hides under taps
        const int pc = y * WW + pxc;
        float cf[8];
        cf[0] = 1.f;
        cf[1] = dep[pc];
        cf[2] = alb[pc]; cf[3] = alb[pc + HW]; cf[4] = alb[pc + 2 * HW];
        cf[5] = nrm[pc]; cf[6] = nrm[pc + HW]; cf[7] = nrm[pc + 2 * HW];

        // ---- horizontal taps for AtA (AtY deferred past the solve) ----
        float W[36];
        htap12(0,  &W[0]);
        htap12(12, &W[12]);
        htap12(24, &W[24]);
        #pragma unroll
        for (int i = 0; i < 8; i++) W[OFF(i)] += 1.0e-4f;

        const bool more = (y + 1 < y0 + RPB);           // wave-uniform

        // prefetch next add-row (HBM-cold): latency hides under the solve
        if (more) load_row(y + 4, pAf, pAy);

        // ---- fp32 LDL^T (sqrt-free); diagonal overwritten with 1/d_i ----
        #pragma unroll
        for (int i = 0; i < 8; i++) {
            #pragma unroll
            for (int k = 0; k < i; k++) {
                const float c = W[OFF(k) + i - k] * W[OFF(k)];   // R_ki/d_k = U_ki
                #pragma unroll
                for (int j = i; j < 8; j++)
                    W[OFF(i) + j - i] = fmaf(-c, W[OFF(k) + j - k], W[OFF(i) + j - i]);
            }
            W[OFF(i)] = frcp_fast(W[OFF(i)]);    // d_i -> 1/d_i in place
        }

        // forward: vt_i = (cf_i - sum_{k<i} R_ki * vt_k) / d_i
        float vt[8];
        #pragma unroll
        for (int i = 0; i < 8; i++) {
            float s = cf[i];
            #pragma unroll
            for (int k = 0; k < i; k++)
                s = fmaf(-W[OFF(k) + i - k], vt[k], s);
            vt[i] = s * W[OFF(i)];
        }
        // back: w_i = vt_i - (1/d_i) * sum_{j>i} R_ij * w_j
        float w[8];
        #pragma unroll
        for (int i = 7; i >= 0; i--) {
            float t = 0.f;
            #pragma unroll
            for (int j = i + 1; j < 8; j++)
                t = fmaf(W[OFF(i) + j - i], w[j], t);
            w[i] = fmaf(-W[OFF(i)], t, vt[i]);
        }

        // prefetch next sub-row (L2-warm): latency hides under AtY taps + dots
        if (more) load_row(y - 3, pSf, pSy);

        // ---- deferred AtY taps (batched) + output dot products:
        //      ALL lanes execute; only the store is predicated ----
        float r[3] = {0.f, 0.f, 0.f};
        {
            float SY[12];
            htap12(36, SY);                   // AtY for i=0..3
            #pragma unroll
            for (int i = 0; i < 4; i++)
                #pragma unroll
                for (int c = 0; c < 3; c++)
                    r[c] = fmaf(w[i], SY[i * 3 + c], r[c]);
            htap12(48, SY);                   // AtY for i=4..7
            #pragma unroll
            for (int i = 0; i < 4; i++)
                #pragma unroll
                for (int c = 0; c < 3; c++)
                    r[c] = fmaf(w[i + 4], SY[i * 3 + c], r[c]);
        }

        if (do_store) {
            const int p = y * WW + px;
            #pragma unroll
            for (int c = 0; c < 3; c++)
                out[c * HW + p] = r[c];
        }
    }
}

extern "C" void kernel_launch(void* const* d_in, const int* in_sizes, int n_in,
                              void* d_out, int out_size, void* d_ws, size_t ws_size,
                              hipStream_t stream) {
    const float* inp = (const float*)d_in[0];
    const float* dep = (const float*)d_in[1];
    const float* alb = (const float*)d_in[2];
    const float* nrm = (const float*)d_in[3];
    float* out = (float*)d_out;
    dim3 grid((WW + OUTW - 1) / OUTW, HH / (RPB * WPB));   // 18 x 64, 256-thr blocks
    ls_sep_kernel<<<grid, dim3(WPB * 64), 0, stream>>>(inp, dep, alb, nrm, out);
}

// Round 2
// 146.606 us; speedup vs baseline: 1.1292x; 1.1292x over previous
//
#include <hip/hip_runtime.h>
#include <math.h>

#define HH 1024
#define WW 1024
#define OUTW 58            // output columns per wave (64 lanes - 6 halo)
#define RPB 4              // output rows per WAVE (vertical slide length)
#define WPB 4              // waves per block (independent y-strips, no barrier)
#define OFF(i) ((i)*8 - (i)*((i)-1)/2)   // packed upper-tri row offset

// ===== R18: add-row-only prefetch, paid for by in-place solve =====
// Hard-won constraints (rounds 4..17):
//  - VGPR bucket MUST stay 128; peak live floats <= ~120 or the allocator
//    spills INSIDE the 128 bucket (r7/r16/r17: WRITE_SIZE 40/39/92 MB).
//    WRITE_SIZE == 13536 KB is the no-spill invariant. R17's dual
//    prefetch (22 extra live) spilled catastrophically -> 96 us.
//  - Cross-lane ops (DPP/bpermute) never inside divergent flow (r8).
//  - No LDS prefetch: s_waitcnt vmcnt(0) drains output stores (r15).
//  - TLP up/down and packed fp32 regressed (r10/r13/r16).
// R18 changes vs champion (56.3 us):
//  - Add-row (HBM-cold) register prefetch ONLY, issued between the AtA
//    htaps and the solve; the LDL^T serial chain is the VMEM shadow.
//    Sub-row stays load-at-top (L2-warm, ~200 cy exposed, cheap).
//  - Solve made explicitly in-place: forward-sub overwrites cf (vt:=cf),
//    back-sub overwrites vt (w:=vt). -16 peak regs pays for the +11
//    prefetch regs. idv folded into W diagonal (as r17).
//  - 6-row preload + iter-y0 skips subtract (removes the exact add/sub
//    cancellation of row y0-4): ~4% fewer instructions.
// Ledger: phaseB ~116, phaseC ~115 (incl pA11), phaseD ~118. All <= ~120.

// DPP move, bound_ctrl=1 (invalid lanes read 0)
template<int CTRL>
__device__ __forceinline__ float dpp0(float x) {
    return __int_as_float(
        __builtin_amdgcn_update_dpp(0, __float_as_int(x), CTRL, 0xf, 0xf, true));
}
// whole-wave shift right by 1 lane (crosses 16-lane row boundaries)
__device__ __forceinline__ float wshr1(float x) { return dpp0<0x138>(x); }

// fp32 reciprocal: v_rcp_f32 + 1 Newton step (~1ulp); LDL^T is sqrt-free
__device__ __forceinline__ float frcp_fast(float s) {
    float r = __builtin_amdgcn_rcpf(s);
    return r * fmaf(-s, r, 2.0f);
}

__global__ __launch_bounds__(WPB * 64, 2) void ls_sep_kernel(
    const float* __restrict__ inp,    // [3,H,W]
    const float* __restrict__ dep,    // [1,H,W]
    const float* __restrict__ alb,    // [3,H,W]
    const float* __restrict__ nrm,    // [3,H,W]
    float* __restrict__ out)          // [3,H,W]
{
    const int L  = threadIdx.x & 63;          // lane 0..63
    const int wv = threadIdx.x >> 6;          // wave 0..3 (independent y-strip)
    const int HW = HH * WW;
    // lane L sums column x; its horizontal window (x-6..x) is centered at x-3
    const int x  = OUTW * blockIdx.x - 3 + L;
    const int y0 = (RPB * WPB) * blockIdx.y + RPB * wv;
    const int px = x - 3;                     // output pixel column for this lane

    const int xc    = min(max(x, 0), WW - 1);
    const float xok = (x >= 0 && x < WW) ? 1.f : 0.f;

    float C[60];                              // running column sums (7 rows in y)
    #pragma unroll
    for (int k = 0; k < 60; k++) C[k] = 0.f;

    // clamped-address loads only; no C update (prefetchable)
    auto load_row = [&](int yy, float (&fv)[8], float (&yv)[3]) {
        const int yc = min(max(yy, 0), HH - 1);
        const int p = yc * WW + xc;
        fv[0] = 1.f;
        fv[1] = dep[p];
        fv[2] = alb[p];
        fv[3] = alb[p + HW];
        fv[4] = alb[p + 2 * HW];
        fv[5] = nrm[p];
        fv[6] = nrm[p + HW];
        fv[7] = nrm[p + 2 * HW];
        yv[0] = inp[p];
        yv[1] = inp[p + HW];
        yv[2] = inp[p + 2 * HW];
    };

    // masked accumulate of a loaded row into the column sums
    auto apply_row = [&](const float (&fv)[8], const float (&yv)[3],
                         int yy, float sgn) {
        const float ok = (yy >= 0 && yy < HH) ? xok : 0.f;
        const float s = sgn * ok;
        float fs[8];
        #pragma unroll
        for (int i = 0; i < 8; i++) fs[i] = fv[i] * s;
        int k = 0;
        #pragma unroll
        for (int i = 0; i < 8; i++)
            #pragma unroll
            for (int j = i; j < 8; j++) { C[k] = fmaf(fs[i], fv[j], C[k]); k++; }
        #pragma unroll
        for (int i = 0; i < 8; i++)
            #pragma unroll
            for (int c = 0; c < 3; c++)
                C[36 + i * 3 + c] = fmaf(fs[i], yv[c], C[36 + i * 3 + c]);
    };

    // prologue prefetch of iter-y0's add-row: fully covered by the preload
    float pAf[8], pAy[3];
    load_row(y0 + 3, pAf, pAy);

    // preload rows y0-3 .. y0+2 (iter y0 skips the subtract; window y0-3..y0+3)
    #pragma unroll 1
    for (int yy = y0 - 3; yy < y0 + 3; yy++) {
        float fv[8], yv[3];
        load_row(yy, fv, yv);
        apply_row(fv, yv, yy, 1.f);
    }

    const int idxm4 = ((L - 4) & 63) << 2;    // bpermute byte index for lane L-4
    const int pxc = min(max(px, 0), WW - 1);
    const bool do_store = (L >= 6) && (px < WW);

    // Batched horizontal 7-tap over lanes L-6..L for 12 values at once.
    // MUST be called by all 64 lanes (cross-lane inside).
    auto htap12 = [&](int base, float* dst) {
        float t2a[12];
        int pma[12];
        #pragma unroll
        for (int j = 0; j < 12; j++) {
            const float xv = C[base + j];
            const float w1 = wshr1(xv);       // C(L-1)
            const float t1 = xv + w1;         // L-1..L
            const float w2 = wshr1(w1);       // C(L-2)
            const float t3 = t1 + w2;         // L-2..L
            const float w3 = wshr1(w2);       // C(L-3)
            t2a[j] = t3 + w3;                 // L-3..L
            pma[j] = __builtin_amdgcn_ds_bpermute(idxm4, __float_as_int(t3));
        }
        #pragma unroll
        for (int j = 0; j < 12; j++)
            dst[j] = t2a[j] + __int_as_float(pma[j]);   // + (L-6..L-4)
    };

    #pragma unroll 1
    for (int y = y0; y < y0 + RPB; y++) {
        // ---- consume prefetched add-row; load+apply sub-row (L2-warm) ----
        apply_row(pAf, pAy, y + 3, 1.f);
        if (y > y0) {                         // wave-uniform branch
            float sf[8], sy[3];
            load_row(y - 4, sf, sy);
            apply_row(sf, sy, y - 4, -1.f);
        }

        // center-pixel features EARLY (L1/L2 hits, hide under taps).
        // cf is destructively renamed: cf -> vt (forward) -> w (backward).
        const int pc = y * WW + pxc;
        float cf[8];
        cf[0] = 1.f;
        cf[1] = dep[pc];
        cf[2] = alb[pc]; cf[3] = alb[pc + HW]; cf[4] = alb[pc + 2 * HW];
        cf[5] = nrm[pc]; cf[6] = nrm[pc + HW]; cf[7] = nrm[pc + 2 * HW];

        // ---- horizontal taps for AtA (AtY deferred past the solve) ----
        float W[36];
        htap12(0,  &W[0]);
        htap12(12, &W[12]);
        htap12(24, &W[24]);
        #pragma unroll
        for (int i = 0; i < 8; i++) W[OFF(i)] += 1.0e-4f;

        const bool more = (y + 1 < y0 + RPB);           // wave-uniform

        // prefetch next add-row (HBM-cold): latency hides under the solve
        if (more) load_row(y + 4, pAf, pAy);

        // ---- fp32 LDL^T (sqrt-free); diagonal overwritten with 1/d_i ----
        #pragma unroll
        for (int i = 0; i < 8; i++) {
            #pragma unroll
            for (int k = 0; k < i; k++) {
                const float c = W[OFF(k) + i - k] * W[OFF(k)];   // R_ki/d_k = U_ki
                #pragma unroll
                for (int j = i; j < 8; j++)
                    W[OFF(i) + j - i] = fmaf(-c, W[OFF(k) + j - k], W[OFF(i) + j - i]);
            }
            W[OFF(i)] = frcp_fast(W[OFF(i)]);    // d_i -> 1/d_i in place
        }

        // forward sub IN PLACE: cf[i] <- vt_i = (cf_i - sum_{k<i} R_ki vt_k)/d_i
        #pragma unroll
        for (int i = 0; i < 8; i++) {
            float s = cf[i];
            #pragma unroll
            for (int k = 0; k < i; k++)
                s = fmaf(-W[OFF(k) + i - k], cf[k], s);
            cf[i] = s * W[OFF(i)];
        }
        // back sub IN PLACE: cf[i] <- w_i = vt_i - (1/d_i) sum_{j>i} R_ij w_j
        #pragma unroll
        for (int i = 7; i >= 0; i--) {
            float t = 0.f;
            #pragma unroll
            for (int j = i + 1; j < 8; j++)
                t = fmaf(W[OFF(i) + j - i], cf[j], t);
            cf[i] = fmaf(-W[OFF(i)], t, cf[i]);
        }

        // ---- deferred AtY taps (batched) + output dot products:
        //      ALL lanes execute; only the store is predicated ----
        float r[3] = {0.f, 0.f, 0.f};
        {
            float SY[12];
            htap12(36, SY);                   // AtY for i=0..3
            #pragma unroll
            for (int i = 0; i < 4; i++)
                #pragma unroll
                for (int c = 0; c < 3; c++)
                    r[c] = fmaf(cf[i], SY[i * 3 + c], r[c]);
            htap12(48, SY);                   // AtY for i=4..7
            #pragma unroll
            for (int i = 0; i < 4; i++)
                #pragma unroll
                for (int c = 0; c < 3; c++)
                    r[c] = fmaf(cf[i + 4], SY[i * 3 + c], r[c]);
        }

        if (do_store) {
            const int p = y * WW + px;
            #pragma unroll
            for (int c = 0; c < 3; c++)
                out[c * HW + p] = r[c];
        }
    }
}

extern "C" void kernel_launch(void* const* d_in, const int* in_sizes, int n_in,
                              void* d_out, int out_size, void* d_ws, size_t ws_size,
                              hipStream_t stream) {
    const float* inp = (const float*)d_in[0];
    const float* dep = (const float*)d_in[1];
    const float* alb = (const float*)d_in[2];
    const float* nrm = (const float*)d_in[3];
    float* out = (float*)d_out;
    dim3 grid((WW + OUTW - 1) / OUTW, HH / (RPB * WPB));   // 18 x 64, 256-thr blocks
    ls_sep_kernel<<<grid, dim3(WPB * 64), 0, stream>>>(inp, dep, alb, nrm, out);
}

// Round 3
// 121.631 us; speedup vs baseline: 1.3610x; 1.2053x over previous
//
#include <hip/hip_runtime.h>
#include <math.h>

#define HH 1024
#define WW 1024
#define OUTW 58            // output columns per wave (64 lanes - 6 halo)
#define RPB 4              // output rows per WAVE (vertical slide length)
#define WPB 4              // waves per block (independent y-strips, no barrier)
#define OFF(i) ((i)*8 - (i)*((i)-1)/2)   // packed upper-tri row offset

// ===== R19: champion structure + fused-DPP prefix htap =====
// Hard-won constraints (rounds 4..18):
//  - VGPR bucket MUST stay 128; peak live floats <= ~120 or the allocator
//    spills INSIDE the 128 bucket. WRITE_SIZE == 13536 KB is the no-spill
//    invariant (r7/r16: 40/39 MB; r17 dual-prefetch: 92 MB; r18
//    single-prefetch + "in-place" solve: 43 MB).
//  - Source-level in-place aliasing saves ZERO registers (compiler SSA-
//    renames); register prefetch across the solve needs >=12 regs of real
//    slack that the champion doesn't have (r18).
//  - Cross-lane ops (DPP/bpermute) never inside divergent flow (r8).
//  - No LDS prefetch: s_waitcnt vmcnt(0) drains output stores (r15).
//  - TLP up/down and packed fp32 regressed (r10/r13/r16).
// R19 changes vs champion (56.3 us):
//  - htap12 rewritten as a 6-step fused-DPP prefix chain:
//    S = xv; 6x { S = xv + wave_shr1(S); }  -> taps L-6..L.
//    Each update_dpp result is single-use -> GCNDPPCombine emits
//    v_add_f32_dpp: 6 VALU, 0 DS ops, ~12 live temps (was 8 ops with
//    3 mov_dpp + 1 ds_bpermute and 24 live temps t2a[12]+pma[12]).
//    Kills 60 bpermutes/iter + all lgkmcnt waits in the taps, and frees
//    ~12 regs at the phase-B peak.
//  - 6-row preload + iter-y0 skips the subtract (drops the exact add/sub
//    cancellation of row y0-4; correctness verified in r17/r18).

// DPP move, bound_ctrl=1 (invalid lanes read 0)
template<int CTRL>
__device__ __forceinline__ float dpp0(float x) {
    return __int_as_float(
        __builtin_amdgcn_update_dpp(0, __float_as_int(x), CTRL, 0xf, 0xf, true));
}
// whole-wave shift right by 1 lane (crosses 16-lane row boundaries)
__device__ __forceinline__ float wshr1(float x) { return dpp0<0x138>(x); }

// fp32 reciprocal: v_rcp_f32 + 1 Newton step (~1ulp); LDL^T is sqrt-free
__device__ __forceinline__ float frcp_fast(float s) {
    float r = __builtin_amdgcn_rcpf(s);
    return r * fmaf(-s, r, 2.0f);
}

__global__ __launch_bounds__(WPB * 64, 2) void ls_sep_kernel(
    const float* __restrict__ inp,    // [3,H,W]
    const float* __restrict__ dep,    // [1,H,W]
    const float* __restrict__ alb,    // [3,H,W]
    const float* __restrict__ nrm,    // [3,H,W]
    float* __restrict__ out)          // [3,H,W]
{
    const int L  = threadIdx.x & 63;          // lane 0..63
    const int wv = threadIdx.x >> 6;          // wave 0..3 (independent y-strip)
    const int HW = HH * WW;
    // lane L sums column x; its horizontal window (x-6..x) is centered at x-3
    const int x  = OUTW * blockIdx.x - 3 + L;
    const int y0 = (RPB * WPB) * blockIdx.y + RPB * wv;
    const int px = x - 3;                     // output pixel column for this lane

    const int xc    = min(max(x, 0), WW - 1);
    const float xok = (x >= 0 && x < WW) ? 1.f : 0.f;

    float C[60];                              // running column sums (7 rows in y)
    #pragma unroll
    for (int k = 0; k < 60; k++) C[k] = 0.f;

    auto acc_row = [&](int yy, float sgn) {
        const int yc = min(max(yy, 0), HH - 1);
        const float ok = (yy >= 0 && yy < HH) ? xok : 0.f;
        const int p = yc * WW + xc;
        float fv[8], yv[3];
        fv[0] = 1.f;
        fv[1] = dep[p];
        fv[2] = alb[p];
        fv[3] = alb[p + HW];
        fv[4] = alb[p + 2 * HW];
        fv[5] = nrm[p];
        fv[6] = nrm[p + HW];
        fv[7] = nrm[p + 2 * HW];
        yv[0] = inp[p];
        yv[1] = inp[p + HW];
        yv[2] = inp[p + 2 * HW];
        const float s = sgn * ok;
        float fs[8];
        #pragma unroll
        for (int i = 0; i < 8; i++) fs[i] = fv[i] * s;
        int k = 0;
        #pragma unroll
        for (int i = 0; i < 8; i++)
            #pragma unroll
            for (int j = i; j < 8; j++) { C[k] = fmaf(fs[i], fv[j], C[k]); k++; }
        #pragma unroll
        for (int i = 0; i < 8; i++)
            #pragma unroll
            for (int c = 0; c < 3; c++)
                C[36 + i * 3 + c] = fmaf(fs[i], yv[c], C[36 + i * 3 + c]);
    };

    // preload rows y0-3 .. y0+2 (iter y0 skips the subtract; window y0-3..y0+3)
    #pragma unroll 1
    for (int yy = y0 - 3; yy < y0 + 3; yy++) acc_row(yy, 1.f);

    const int pxc = min(max(px, 0), WW - 1);
    const bool do_store = (L >= 6) && (px < WW);

    // Batched horizontal 7-tap over lanes L-6..L for 12 values at once.
    // 6-step fused-DPP prefix chain: S_k covers lanes L-k..L; each
    // update_dpp result is single-use so it fuses into v_add_f32_dpp.
    // MUST be called by all 64 lanes (cross-lane inside).
    auto htap12 = [&](int base, float* dst) {
        #pragma unroll
        for (int j = 0; j < 12; j++) {
            const float xv = C[base + j];
            float S = xv;
            #pragma unroll
            for (int t = 0; t < 6; t++) S = xv + wshr1(S);
            dst[j] = S;
        }
    };

    #pragma unroll 1
    for (int y = y0; y < y0 + RPB; y++) {
        acc_row(y + 3, 1.f);
        if (y > y0) acc_row(y - 4, -1.f);     // wave-uniform branch

        // center-pixel features EARLY: global-load latency hides under taps
        const int pc = y * WW + pxc;
        float cf[8];
        cf[0] = 1.f;
        cf[1] = dep[pc];
        cf[2] = alb[pc]; cf[3] = alb[pc + HW]; cf[4] = alb[pc + 2 * HW];
        cf[5] = nrm[pc]; cf[6] = nrm[pc + HW]; cf[7] = nrm[pc + 2 * HW];

        // ---- horizontal taps for AtA (AtY deferred past the solve) ----
        float W[36];
        htap12(0,  &W[0]);
        htap12(12, &W[12]);
        htap12(24, &W[24]);
        #pragma unroll
        for (int i = 0; i < 8; i++) W[OFF(i)] += 1.0e-4f;

        // ---- fp32 LDL^T (sqrt-free). W row i keeps R_ij = d_i*U_ij ----
        float idv[8];
        #pragma unroll
        for (int i = 0; i < 8; i++) {
            #pragma unroll
            for (int k = 0; k < i; k++) {
                const float c = W[OFF(k) + i - k] * idv[k];   // U_ki
                #pragma unroll
                for (int j = i; j < 8; j++)
                    W[OFF(i) + j - i] = fmaf(-c, W[OFF(k) + j - k], W[OFF(i) + j - i]);
            }
            idv[i] = frcp_fast(W[OFF(i)]);    // 1/d_i
        }

        // forward: vt_i = idv_i * (cf_i - sum_{k<i} R_ki * vt_k)
        float vt[8];
        #pragma unroll
        for (int i = 0; i < 8; i++) {
            float s = cf[i];
            #pragma unroll
            for (int k = 0; k < i; k++)
                s = fmaf(-W[OFF(k) + i - k], vt[k], s);
            vt[i] = s * idv[i];
        }
        // back: w_i = vt_i - idv_i * sum_{j>i} R_ij * w_j
        float w[8];
        #pragma unroll
        for (int i = 7; i >= 0; i--) {
            float t = 0.f;
            #pragma unroll
            for (int j = i + 1; j < 8; j++)
                t = fmaf(W[OFF(i) + j - i], w[j], t);
            w[i] = fmaf(-idv[i], t, vt[i]);
        }

        // ---- deferred AtY taps (batched) + output dot products:
        //      ALL lanes execute; only the store is predicated ----
        float r[3] = {0.f, 0.f, 0.f};
        {
            float SY[12];
            htap12(36, SY);                   // AtY for i=0..3
            #pragma unroll
            for (int i = 0; i < 4; i++)
                #pragma unroll
                for (int c = 0; c < 3; c++)
                    r[c] = fmaf(w[i], SY[i * 3 + c], r[c]);
            htap12(48, SY);                   // AtY for i=4..7
            #pragma unroll
            for (int i = 0; i < 4; i++)
                #pragma unroll
                for (int c = 0; c < 3; c++)
                    r[c] = fmaf(w[i + 4], SY[i * 3 + c], r[c]);
        }

        if (do_store) {
            const int p = y * WW + px;
            #pragma unroll
            for (int c = 0; c < 3; c++)
                out[c * HW + p] = r[c];
        }
    }
}

extern "C" void kernel_launch(void* const* d_in, const int* in_sizes, int n_in,
                              void* d_out, int out_size, void* d_ws, size_t ws_size,
                              hipStream_t stream) {
    const float* inp = (const float*)d_in[0];
    const float* dep = (const float*)d_in[1];
    const float* alb = (const float*)d_in[2];
    const float* nrm = (const float*)d_in[3];
    float* out = (float*)d_out;
    dim3 grid((WW + OUTW - 1) / OUTW, HH / (RPB * WPB));   // 18 x 64, 256-thr blocks
    ls_sep_kernel<<<grid, dim3(WPB * 64), 0, stream>>>(inp, dep, alb, nrm, out);
}